// Round 1
// baseline (245.090 us; speedup 1.0000x reference)
//
#include <hip/hip_runtime.h>
#include <math.h>

typedef unsigned int   uint;
typedef unsigned short ushort;

#define N_NODES 50000
#define DIM     128
#define N_EDGES 800000
#define N_UID   4096
#define LN_EPS  1e-5f
#define RST     132   // padded LDS row stride for fp32 y (132*4 B)
#define NBUCK   196   // ceil(50000/256) buckets of 256 nodes
#define PCHUNK  4096  // edges per part block

typedef __attribute__((ext_vector_type(8))) short bf16x8;
typedef __attribute__((ext_vector_type(4))) float f32x4;
typedef __attribute__((ext_vector_type(2))) float f32x2;
typedef __attribute__((ext_vector_type(4))) uint  u32x4;

// ---- bf16 helpers (storage only; math fp32) ----
__device__ __forceinline__ float bf_lo(uint u) { return __builtin_bit_cast(float, u << 16); }
__device__ __forceinline__ float bf_hi(uint u) { return __builtin_bit_cast(float, u & 0xffff0000u); }
__device__ __forceinline__ uint pack_bf16(float a, float b) {   // RNE
    uint ua = __builtin_bit_cast(uint, a);
    uint ub = __builtin_bit_cast(uint, b);
    uint ra = (ua + 0x7fffu + ((ua >> 16) & 1u)) >> 16;
    uint rb = (ub + 0x7fffu + ((ub >> 16) & 1u)) >> 16;
    return ra | (rb << 16);
}

// ---------- prep: emb -> bf16, W -> bf16, zero bucket histogram + zero pad rows ----------
__global__ __launch_bounds__(256) void prep_kernel(const float* __restrict__ emb, ushort* __restrict__ E,
                                                   const float* __restrict__ W, ushort* __restrict__ WB,
                                                   int* __restrict__ bhist,
                                                   ushort* __restrict__ T1, ushort* __restrict__ T2) {
    int i = blockIdx.x * 256 + threadIdx.x;
    if (i < N_NODES * DIM / 4) {
        const float4 v = ((const float4*)emb)[i];
        uint2 p;
        p.x = pack_bf16(v.x, v.y);
        p.y = pack_bf16(v.z, v.w);
        ((uint2*)E)[i] = p;
    }
    if (i < 3 * DIM * DIM / 4) {
        const float4 v = ((const float4*)W)[i];
        uint2 p;
        p.x = pack_bf16(v.x, v.y);
        p.y = pack_bf16(v.z, v.w);
        ((uint2*)WB)[i] = p;
    }
    if (i < NBUCK) bhist[i] = 0;
    if (i < DIM / 4) {               // zero row N_NODES of each feature buffer (tail-clamp target)
        const uint2 z = make_uint2(0u, 0u);
        ((uint2*)(E  + (size_t)N_NODES * DIM))[i] = z;
        ((uint2*)(T1 + (size_t)N_NODES * DIM))[i] = z;
        ((uint2*)(T2 + (size_t)N_NODES * DIM))[i] = z;
    }
}

// ---------- bucket histogram: LDS hist per block, few global atomics ----------
__global__ __launch_bounds__(256) void bhist_kernel(const int* __restrict__ dst, int* __restrict__ bhist) {
    __shared__ int h[256];
    const int t = threadIdx.x;
    h[t] = 0;
    __syncthreads();
    for (int e = blockIdx.x * 256 + t; e < N_EDGES; e += gridDim.x * 256)
        atomicAdd(&h[dst[e] >> 8], 1);
    __syncthreads();
    if (t < NBUCK && h[t]) atomicAdd(&bhist[t], h[t]);
}

// ---------- scan bucket counts (1 block) ----------
__global__ __launch_bounds__(256) void bscan_kernel(const int* __restrict__ bhist, int* __restrict__ bbase,
                                                    int* __restrict__ bcur, int* __restrict__ off) {
    __shared__ int sh[256];
    const int t = threadIdx.x;
    const int v = (t < NBUCK) ? bhist[t] : 0;
    sh[t] = v;
    __syncthreads();
    for (int o = 1; o < 256; o <<= 1) {
        int x = (t >= o) ? sh[t - o] : 0;
        __syncthreads();
        sh[t] += x;
        __syncthreads();
    }
    const int excl = sh[t] - v;
    if (t < NBUCK) { bbase[t] = excl; bcur[t] = excl; }
    if (t == NBUCK - 1) bbase[NBUCK] = excl + v;   // == N_EDGES
    if (t == 0) off[N_NODES] = N_EDGES;
}

// ---------- partition: block-aggregated reservation (one atomic per block-bucket) ----------
__global__ __launch_bounds__(256) void part_kernel(const int* __restrict__ src, const int* __restrict__ dst,
                                                   int* __restrict__ bcur, int2* __restrict__ pak) {
    __shared__ int h[256];
    __shared__ int base[256];
    __shared__ int cur[256];
    const int t  = threadIdx.x;
    const int e0 = blockIdx.x * PCHUNK;
    const int e1 = min(e0 + PCHUNK, N_EDGES);
    h[t] = 0;
    __syncthreads();
    for (int i = e0 + t; i < e1; i += 256)
        atomicAdd(&h[dst[i] >> 8], 1);
    __syncthreads();
    if (t < NBUCK && h[t]) base[t] = atomicAdd(&bcur[t], h[t]);
    cur[t] = 0;
    __syncthreads();
    for (int i = e0 + t; i < e1; i += 256) {
        const int s = src[i], d = dst[i];
        const int b = d >> 8;
        const int q = atomicAdd(&cur[b], 1);
        pak[base[b] + q] = make_int2(s, d);
    }
}

// ---------- per-bucket CSR: count/scan/scatter in LDS; csr writes L2-local ----------
__global__ __launch_bounds__(256) void bucket_kernel(const int2* __restrict__ pak, const int* __restrict__ bbase,
                                                     int* __restrict__ off, int* __restrict__ csr) {
    __shared__ int cnt[256];
    __shared__ int pos[256];
    const int b = blockIdx.x, t = threadIdx.x;
    const int e0 = bbase[b], e1 = bbase[b + 1], m = e1 - e0;
    cnt[t] = 0;
    __syncthreads();
    for (int i = t; i < m; i += 256) atomicAdd(&cnt[pak[e0 + i].y & 255], 1);
    __syncthreads();
    const int v = cnt[t];
    pos[t] = v;
    __syncthreads();
    for (int o = 1; o < 256; o <<= 1) {
        int x = (t >= o) ? pos[t - o] : 0;
        __syncthreads();
        pos[t] += x;
        __syncthreads();
    }
    const int excl = pos[t] - v;
    const int node = b * 256 + t;
    if (node < N_NODES) off[node] = e0 + excl;
    __syncthreads();
    pos[t] = excl;                               // reuse as cursor
    __syncthreads();
    for (int i = t; i < m; i += 256) {
        const int2 p = pak[e0 + i];
        const int q = atomicAdd(&pos[p.y & 255], 1);
        csr[e0 + q] = p.x;                       // within bucket's 16KB window
    }
}

// ---------- aggregation: barrier-free, LDS-free. 256 thr = 16 streams x 16 lanes ----------
// Each stream owns one node: x_mean = (self + sum_{src in N(n)} fin[src]) / (deg+1),
// accumulated fp32 (f32x2 -> v_pk_add_f32), written bf16 to xm[slot].
// Pad indices clamp to zero-row N_NODES (exact +0.0f, L1-hot) -> no mask path.
__global__ __launch_bounds__(256) void agg_kernel(
    const ushort* __restrict__ fin, ushort* __restrict__ xm,
    const int* __restrict__ off, const int* __restrict__ csr,
    const int* __restrict__ uidmap, int nrows)
{
    const int t    = threadIdx.x;
    const int lx   = t & 15;                 // covers dims lx*8 .. lx*8+7
    const int st   = t >> 4;                 // stream 0..15
    const int slot = blockIdx.x * 16 + st;
    if (slot >= nrows) return;
    const int n = uidmap ? uidmap[slot] : slot;

    // self row (issue early; independent of off/csr chain)
    const uint4 q0 = ((const uint4*)(fin + (size_t)n * DIM))[lx];
    const int d0 = off[n];
    const int d1 = off[n + 1];
    const int deg = d1 - d0;

    f32x2 a[4];
    a[0] = f32x2{bf_lo(q0.x), bf_hi(q0.x)};
    a[1] = f32x2{bf_lo(q0.y), bf_hi(q0.y)};
    a[2] = f32x2{bf_lo(q0.z), bf_hi(q0.z)};
    a[3] = f32x2{bf_lo(q0.w), bf_hi(q0.w)};

    const int rounds = (deg + 7) >> 3;
    int id[8];
    int e = d0;
    if (rounds > 0) {
        #pragma unroll
        for (int k = 0; k < 8; ++k) {
            const int ee = e + k;
            const int c = csr[ee];           // csr padded +16 ints; value discarded if OOB
            id[k] = (ee < d1) ? c : N_NODES; // clamp to zero row
        }
    }
    for (int r = 0; r < rounds; ++r) {
        uint4 v[8];
        #pragma unroll
        for (int k = 0; k < 8; ++k)
            v[k] = ((const uint4*)(fin + (size_t)id[k] * DIM))[lx];
        if (r + 1 < rounds) {                // prefetch next round's indices
            #pragma unroll
            for (int k = 0; k < 8; ++k) {
                const int ee = e + 8 + k;
                const int c = csr[ee];
                id[k] = (ee < d1) ? c : N_NODES;
            }
        }
        #pragma unroll
        for (int k = 0; k < 8; ++k) {
            a[0] += f32x2{bf_lo(v[k].x), bf_hi(v[k].x)};
            a[1] += f32x2{bf_lo(v[k].y), bf_hi(v[k].y)};
            a[2] += f32x2{bf_lo(v[k].z), bf_hi(v[k].z)};
            a[3] += f32x2{bf_lo(v[k].w), bf_hi(v[k].w)};
        }
        e += 8;
    }

    const float iv = 1.0f / (float)(deg + 1);
    uint4 p;
    p.x = pack_bf16(a[0].x * iv, a[0].y * iv);
    p.y = pack_bf16(a[1].x * iv, a[1].y * iv);
    p.z = pack_bf16(a[2].x * iv, a[2].y * iv);
    p.w = pack_bf16(a[3].x * iv, a[3].y * iv);
    *((uint4*)(xm + (size_t)slot * DIM + lx * 8)) = p;
}

// ---------- GEMM + LN + ELU: 512 thr, 32 rows/block, in-place safe ----------
// A-fragments straight from global x_mean (no staging LDS). 8 waves:
// wave w: rows (w>>2)*16, cols (w&3)*32 (2 col-tiles of 16).
// C/D: col = lane&15, row = (lane>>4)*4 + reg   [measured m89]
template <bool OUT_BF16>
__global__ __launch_bounds__(512) void gemmln_kernel(
    const ushort* xm, void* fout,            // may alias (in-place): no __restrict
    const ushort* __restrict__ wb, const float* __restrict__ bias,
    const float* __restrict__ gamma, const float* __restrict__ beta, int nrows)
{
    __shared__ float ys[32 * RST];           // 16896 B
    const int t = threadIdx.x;
    const int rows = blockIdx.x * 32;

    // ---- MFMA y = x @ W^T ----
    {
        const int wave = t >> 6, lane = t & 63;
        const int row_off = (wave >> 2) * 16;
        const int col_off = (wave & 3) * 32;
        const int lm   = lane & 15;
        const int quad = lane >> 4;
        const int arow = min(rows + row_off + lm, nrows - 1);   // guard last block
        const ushort* xrow = xm + (size_t)arow * DIM + quad * 8;
        const ushort* wrow = wb + (size_t)(col_off + lm) * DIM + quad * 8;
        f32x4 acc[2] = {f32x4{0,0,0,0}, f32x4{0,0,0,0}};
        #pragma unroll
        for (int kk = 0; kk < 4; ++kk) {
            const bf16x8 af = __builtin_bit_cast(bf16x8, *(const u32x4*)(xrow + kk * 32));
            #pragma unroll
            for (int c = 0; c < 2; ++c) {
                const bf16x8 bfr = __builtin_bit_cast(bf16x8,
                    *(const u32x4*)(wrow + (size_t)c * 16 * DIM + kk * 32));
                acc[c] = __builtin_amdgcn_mfma_f32_16x16x32_bf16(af, bfr, acc[c], 0, 0, 0);
            }
        }
        #pragma unroll
        for (int c = 0; c < 2; ++c) {
            #pragma unroll
            for (int r = 0; r < 4; ++r)
                ys[(row_off + quad * 4 + r) * RST + col_off + c * 16 + lm] = acc[c][r];
        }
    }
    __syncthreads();

    // ---- LN + ELU; 16 threads per row, 8 dims each ----
    {
        const int r   = t >> 4;              // row 0..31
        const int seg = t & 15;              // 0..15
        const int db  = seg * 8;
        const float* yr = ys + r * RST + db;
        float vs[8];
        {
            const float4 y0 = ((const float4*)yr)[0];
            const float4 y1 = ((const float4*)yr)[1];
            const float4 b0 = ((const float4*)(bias + db))[0];
            const float4 b1 = ((const float4*)(bias + db))[1];
            vs[0] = y0.x + b0.x; vs[1] = y0.y + b0.y; vs[2] = y0.z + b0.z; vs[3] = y0.w + b0.w;
            vs[4] = y1.x + b1.x; vs[5] = y1.y + b1.y; vs[6] = y1.z + b1.z; vs[7] = y1.w + b1.w;
        }
        float s1 = 0.0f, s2 = 0.0f;
        #pragma unroll
        for (int i = 0; i < 8; ++i) { s1 += vs[i]; s2 += vs[i] * vs[i]; }
        #pragma unroll
        for (int m = 1; m < 16; m <<= 1) {
            s1 += __shfl_xor(s1, m);
            s2 += __shfl_xor(s2, m);
        }
        const float mu  = s1 * (1.0f / 128.0f);
        const float var = s2 * (1.0f / 128.0f) - mu * mu;
        const float rs  = rsqrtf(var + LN_EPS);
        float ov[8];
        {
            const float4 g0 = ((const float4*)(gamma + db))[0];
            const float4 g1 = ((const float4*)(gamma + db))[1];
            const float4 t0 = ((const float4*)(beta + db))[0];
            const float4 t1 = ((const float4*)(beta + db))[1];
            float z;
            z = (vs[0] - mu) * rs * g0.x + t0.x; ov[0] = (z > 0.0f) ? z : __expf(z) - 1.0f;
            z = (vs[1] - mu) * rs * g0.y + t0.y; ov[1] = (z > 0.0f) ? z : __expf(z) - 1.0f;
            z = (vs[2] - mu) * rs * g0.z + t0.z; ov[2] = (z > 0.0f) ? z : __expf(z) - 1.0f;
            z = (vs[3] - mu) * rs * g0.w + t0.w; ov[3] = (z > 0.0f) ? z : __expf(z) - 1.0f;
            z = (vs[4] - mu) * rs * g1.x + t1.x; ov[4] = (z > 0.0f) ? z : __expf(z) - 1.0f;
            z = (vs[5] - mu) * rs * g1.y + t1.y; ov[5] = (z > 0.0f) ? z : __expf(z) - 1.0f;
            z = (vs[6] - mu) * rs * g1.z + t1.z; ov[6] = (z > 0.0f) ? z : __expf(z) - 1.0f;
            z = (vs[7] - mu) * rs * g1.w + t1.w; ov[7] = (z > 0.0f) ? z : __expf(z) - 1.0f;
        }
        const int n = rows + r;
        if (n < nrows) {
            if (OUT_BF16) {
                uint4 p;
                p.x = pack_bf16(ov[0], ov[1]);
                p.y = pack_bf16(ov[2], ov[3]);
                p.z = pack_bf16(ov[4], ov[5]);
                p.w = pack_bf16(ov[6], ov[7]);
                *((uint4*)((ushort*)fout + (size_t)n * DIM + db)) = p;
            } else {
                float* op = (float*)fout + (size_t)n * DIM + db;
                ((float4*)op)[0] = make_float4(ov[0], ov[1], ov[2], ov[3]);
                ((float4*)op)[1] = make_float4(ov[4], ov[5], ov[6], ov[7]);
            }
        }
    }
}

extern "C" void kernel_launch(void* const* d_in, const int* in_sizes, int n_in,
                              void* d_out, int out_size, void* d_ws, size_t ws_size,
                              hipStream_t stream) {
    const float* emb   = (const float*)d_in[0];
    const float* W     = (const float*)d_in[1];
    const float* bias  = (const float*)d_in[2];
    const float* gamma = (const float*)d_in[3];
    const float* beta  = (const float*)d_in[4];
    const int*   src   = (const int*)d_in[5];
    const int*   dst   = (const int*)d_in[6];
    const int*   uid   = (const int*)d_in[7];

    // workspace layout (~46 MB); feature buffers have a zero pad row at index N_NODES
    const size_t FROW = (size_t)(N_NODES + 1) * DIM;
    ushort* E    = (ushort*)d_ws;                     // (N+1)*128 bf16 (embedding + zero row)
    ushort* T1   = E + FROW;                          // (N+1)*128 bf16
    ushort* T2   = T1 + FROW;                         // (N+1)*128 bf16
    ushort* WB   = T2 + FROW;                         // 3*128*128 bf16
    int*    off  = (int*)(WB + 3 * DIM * DIM);        // 50001 (+pad to 50004)
    int*    bhist = off + (N_NODES + 4);              // 256
    int*    bbase = bhist + 256;                      // 260 (NBUCK+1 +pad)
    int*    bcur  = bbase + 260;                      // 256
    int2*   pak   = (int2*)(bcur + 256);              // 800000 int2 (8B aligned)
    int*    csr   = (int*)(pak + N_EDGES);            // 800000 (+16 overread pad)

    prep_kernel<<<(N_NODES * DIM / 4 + 255) / 256, 256, 0, stream>>>(emb, E, W, WB, bhist, T1, T2);
    bhist_kernel<<<512, 256, 0, stream>>>(dst, bhist);
    bscan_kernel<<<1, 256, 0, stream>>>(bhist, bbase, bcur, off);
    part_kernel<<<(N_EDGES + PCHUNK - 1) / PCHUNK, 256, 0, stream>>>(src, dst, bcur, pak);
    bucket_kernel<<<NBUCK, 256, 0, stream>>>(pak, bbase, off, csr);

    const int ablk = N_NODES / 16;                    // 3125 (exact)
    const int gblk = (N_NODES + 31) / 32;             // 1563

    // layer 1: E -> T1 (agg), T1 -> T1 (gemm+ln in place)
    agg_kernel<<<ablk, 256, 0, stream>>>(E, T1, off, csr, nullptr, N_NODES);
    gemmln_kernel<true><<<gblk, 512, 0, stream>>>(T1, T1, WB, bias, gamma, beta, N_NODES);
    // layer 2: T1 -> T2 -> T2
    agg_kernel<<<ablk, 256, 0, stream>>>(T1, T2, off, csr, nullptr, N_NODES);
    gemmln_kernel<true><<<gblk, 512, 0, stream>>>(T2, T2, WB + DIM * DIM,
                                                  bias + DIM, gamma + DIM, beta + DIM, N_NODES);
    // layer 3: only uid nodes — agg into T1 (first 4096 rows), fp32 out
    agg_kernel<<<N_UID / 16, 256, 0, stream>>>(T2, T1, off, csr, uid, N_UID);
    gemmln_kernel<false><<<N_UID / 32, 512, 0, stream>>>(T1, (float*)d_out, WB + 2 * DIM * DIM,
                                                         bias + 2 * DIM, gamma + 2 * DIM,
                                                         beta + 2 * DIM, N_UID);
}

// Round 2
// 231.398 us; speedup vs baseline: 1.0592x; 1.0592x over previous
//
#include <hip/hip_runtime.h>
#include <math.h>

typedef unsigned int   uint;
typedef unsigned short ushort;

#define N_NODES 50000
#define DIM     128
#define N_EDGES 800000
#define N_UID   4096
#define LN_EPS  1e-5f
#define RST     132   // padded LDS row stride for fp32 y (132*4 B)
#define XST     136   // padded LDS row stride for bf16 x (136*2=272 B -> 2-way alias, free)
#define NBUCK   196   // ceil(50000/256) buckets of 256 nodes
#define PCHUNK  4096  // edges per part block

typedef __attribute__((ext_vector_type(8))) short bf16x8;
typedef __attribute__((ext_vector_type(4))) float f32x4;
typedef __attribute__((ext_vector_type(2))) float f32x2;
typedef __attribute__((ext_vector_type(4))) uint  u32x4;

// ---- bf16 helpers (storage only; math fp32) ----
__device__ __forceinline__ float bf_lo(uint u) { return __builtin_bit_cast(float, u << 16); }
__device__ __forceinline__ float bf_hi(uint u) { return __builtin_bit_cast(float, u & 0xffff0000u); }
__device__ __forceinline__ uint pack_bf16(float a, float b) {   // RNE
    uint ua = __builtin_bit_cast(uint, a);
    uint ub = __builtin_bit_cast(uint, b);
    uint ra = (ua + 0x7fffu + ((ua >> 16) & 1u)) >> 16;
    uint rb = (ub + 0x7fffu + ((ub >> 16) & 1u)) >> 16;
    return ra | (rb << 16);
}

// ---------- prep: emb/W -> bf16, zero pad rows, zero hist/mark/cnt ----------
__global__ __launch_bounds__(256) void prep_kernel(const float* __restrict__ emb, ushort* __restrict__ E,
                                                   const float* __restrict__ W, ushort* __restrict__ WB,
                                                   int* __restrict__ bhist,
                                                   ushort* __restrict__ T1, ushort* __restrict__ T2,
                                                   int* __restrict__ mark, int* __restrict__ cnt) {
    int i = blockIdx.x * 256 + threadIdx.x;
    if (i < N_NODES * DIM / 4) {
        const float4 v = ((const float4*)emb)[i];
        uint2 p;
        p.x = pack_bf16(v.x, v.y);
        p.y = pack_bf16(v.z, v.w);
        ((uint2*)E)[i] = p;
    }
    if (i < 3 * DIM * DIM / 4) {
        const float4 v = ((const float4*)W)[i];
        uint2 p;
        p.x = pack_bf16(v.x, v.y);
        p.y = pack_bf16(v.z, v.w);
        ((uint2*)WB)[i] = p;
    }
    if (i < NBUCK) bhist[i] = 0;
    if (i < N_NODES) mark[i] = 0;
    if (i == 0) cnt[0] = 0;
    if (i < DIM / 4) {               // zero row N_NODES of each feature buffer (tail-clamp target)
        const uint2 z = make_uint2(0u, 0u);
        ((uint2*)(E  + (size_t)N_NODES * DIM))[i] = z;
        ((uint2*)(T1 + (size_t)N_NODES * DIM))[i] = z;
        ((uint2*)(T2 + (size_t)N_NODES * DIM))[i] = z;
    }
}

// ---------- bucket histogram: LDS hist per block, few global atomics ----------
__global__ __launch_bounds__(256) void bhist_kernel(const int* __restrict__ dst, int* __restrict__ bhist) {
    __shared__ int h[256];
    const int t = threadIdx.x;
    h[t] = 0;
    __syncthreads();
    for (int e = blockIdx.x * 256 + t; e < N_EDGES; e += gridDim.x * 256)
        atomicAdd(&h[dst[e] >> 8], 1);
    __syncthreads();
    if (t < NBUCK && h[t]) atomicAdd(&bhist[t], h[t]);
}

// ---------- scan bucket counts (1 block) ----------
__global__ __launch_bounds__(256) void bscan_kernel(const int* __restrict__ bhist, int* __restrict__ bbase,
                                                    int* __restrict__ bcur, int* __restrict__ off) {
    __shared__ int sh[256];
    const int t = threadIdx.x;
    const int v = (t < NBUCK) ? bhist[t] : 0;
    sh[t] = v;
    __syncthreads();
    for (int o = 1; o < 256; o <<= 1) {
        int x = (t >= o) ? sh[t - o] : 0;
        __syncthreads();
        sh[t] += x;
        __syncthreads();
    }
    const int excl = sh[t] - v;
    if (t < NBUCK) { bbase[t] = excl; bcur[t] = excl; }
    if (t == NBUCK - 1) bbase[NBUCK] = excl + v;   // == N_EDGES
    if (t == 0) off[N_NODES] = N_EDGES;
}

// ---------- partition: block-aggregated reservation; pak packed (src<<8)|(dst&255) ----------
__global__ __launch_bounds__(256) void part_kernel(const int* __restrict__ src, const int* __restrict__ dst,
                                                   int* __restrict__ bcur, int* __restrict__ pak) {
    __shared__ int h[256];
    __shared__ int base[256];
    __shared__ int cur[256];
    const int t  = threadIdx.x;
    const int e0 = blockIdx.x * PCHUNK;
    const int e1 = min(e0 + PCHUNK, N_EDGES);
    h[t] = 0;
    __syncthreads();
    for (int i = e0 + t; i < e1; i += 256)
        atomicAdd(&h[dst[i] >> 8], 1);
    __syncthreads();
    if (t < NBUCK && h[t]) base[t] = atomicAdd(&bcur[t], h[t]);
    cur[t] = 0;
    __syncthreads();
    for (int i = e0 + t; i < e1; i += 256) {
        const int s = src[i], d = dst[i];
        const int b = d >> 8;
        const int q = atomicAdd(&cur[b], 1);
        pak[base[b] + q] = (s << 8) | (d & 255);
    }
}

// ---------- per-bucket CSR: count/scan/scatter in LDS ----------
__global__ __launch_bounds__(256) void bucket_kernel(const int* __restrict__ pak, const int* __restrict__ bbase,
                                                     int* __restrict__ off, int* __restrict__ csr) {
    __shared__ int cnt[256];
    __shared__ int pos[256];
    const int b = blockIdx.x, t = threadIdx.x;
    const int e0 = bbase[b], e1 = bbase[b + 1], m = e1 - e0;
    cnt[t] = 0;
    __syncthreads();
    for (int i = t; i < m; i += 256) atomicAdd(&cnt[pak[e0 + i] & 255], 1);
    __syncthreads();
    const int v = cnt[t];
    pos[t] = v;
    __syncthreads();
    for (int o = 1; o < 256; o <<= 1) {
        int x = (t >= o) ? pos[t - o] : 0;
        __syncthreads();
        pos[t] += x;
        __syncthreads();
    }
    const int excl = pos[t] - v;
    const int node = b * 256 + t;
    if (node < N_NODES) off[node] = e0 + excl;
    __syncthreads();
    pos[t] = excl;                               // reuse as cursor
    __syncthreads();
    for (int i = t; i < m; i += 256) {
        const int p = pak[e0 + i];
        const int q = atomicAdd(&pos[p & 255], 1);
        csr[e0 + q] = p >> 8;                    // within bucket's window
    }
}

// ---------- mark layer-2 support set: uid + in-neighbors of uid ----------
__global__ __launch_bounds__(256) void mark_kernel(const int* __restrict__ uid, const int* __restrict__ off,
                                                   const int* __restrict__ csr, int* __restrict__ mark) {
    const int i = blockIdx.x * 256 + threadIdx.x;
    if (i >= N_UID) return;
    const int n = uid[i];
    mark[n] = 1;
    const int d0 = off[n], d1 = off[n + 1];
    for (int e = d0; e < d1; ++e) mark[csr[e]] = 1;
}

// ---------- compact mark -> worklist (unordered; per-node results order-invariant) ----------
__global__ __launch_bounds__(256) void compact_kernel(const int* __restrict__ mark, int* __restrict__ wl,
                                                      int* __restrict__ cnt) {
    const int i = blockIdx.x * 256 + threadIdx.x;
    if (i < N_NODES && mark[i]) wl[atomicAdd(cnt, 1)] = i;
}

// ---------- fused layer: agg (barrier-free phase) + MFMA GEMM + LN + ELU ----------
// 512 threads, 32 nodes/block. Agg: one 16-lane stream per node, 8 rows in
// flight, f32x2 packed accum, zero-row tail clamp. One barrier. Then 8 waves:
// wave w: rows (w>>2)*16, cols (w&3)*32 (2 col-tiles of 16).
// C/D: col = lane&15, row = (lane>>4)*4 + reg   [measured m89]
template <bool OUT_BF16, bool OUT_BY_NODE>
__global__ __launch_bounds__(512) void layer_kernel(
    const ushort* __restrict__ fin, void* __restrict__ fout,
    const int* __restrict__ off, const int* __restrict__ csr,
    const int* __restrict__ uidmap, const ushort* __restrict__ wb,
    const float* __restrict__ bias, const float* __restrict__ gamma,
    const float* __restrict__ beta, int nrows, const int* __restrict__ nrows_dyn)
{
    __shared__ ushort xs[32 * XST];   // 8704 B  (bf16 x_mean)
    __shared__ float  ys[32 * RST];   // 16896 B (fp32 y)
    const int t = threadIdx.x;
    const int nr = nrows_dyn ? *nrows_dyn : nrows;
    const int rows = blockIdx.x * 32;
    if (rows >= nr) return;           // block-uniform early exit (dynamic worklist tail)

    // ---- phase 1: aggregate (barrier-free, 8 rows in flight) ----
    {
        const int lx   = t & 15;                 // covers elems lx*8 .. lx*8+7
        const int st   = t >> 4;                 // node slot 0..31
        const int slot = rows + st;
        const bool valid = slot < nr;
        int n = 0;
        if (valid) n = uidmap ? uidmap[slot] : slot;
        const uint4 q0 = ((const uint4*)(fin + (size_t)n * DIM))[lx];
        const int d0 = off[n];
        int d1 = off[n + 1];
        if (!valid) d1 = d0;
        const int deg = d1 - d0;

        f32x2 a[4];
        a[0] = f32x2{bf_lo(q0.x), bf_hi(q0.x)};
        a[1] = f32x2{bf_lo(q0.y), bf_hi(q0.y)};
        a[2] = f32x2{bf_lo(q0.z), bf_hi(q0.z)};
        a[3] = f32x2{bf_lo(q0.w), bf_hi(q0.w)};

        const int rounds = (deg + 7) >> 3;       // tail rows clamp to zero row N_NODES
        int id[8];
        int e = d0;
        if (rounds > 0) {
            #pragma unroll
            for (int k = 0; k < 8; ++k) {
                const int ee = e + k;
                const int c = csr[ee];           // csr padded +16 ints
                id[k] = (ee < d1) ? c : N_NODES;
            }
        }
        for (int r = 0; r < rounds; ++r) {
            uint4 v[8];
            #pragma unroll
            for (int k = 0; k < 8; ++k)
                v[k] = ((const uint4*)(fin + (size_t)id[k] * DIM))[lx];
            if (r + 1 < rounds) {                // prefetch next round's indices
                #pragma unroll
                for (int k = 0; k < 8; ++k) {
                    const int ee = e + 8 + k;
                    const int c = csr[ee];
                    id[k] = (ee < d1) ? c : N_NODES;
                }
            }
            #pragma unroll
            for (int k = 0; k < 8; ++k) {
                a[0] += f32x2{bf_lo(v[k].x), bf_hi(v[k].x)};
                a[1] += f32x2{bf_lo(v[k].y), bf_hi(v[k].y)};
                a[2] += f32x2{bf_lo(v[k].z), bf_hi(v[k].z)};
                a[3] += f32x2{bf_lo(v[k].w), bf_hi(v[k].w)};
            }
            e += 8;
        }

        const float iv = 1.0f / (float)(deg + 1);
        uint4 p;
        p.x = pack_bf16(a[0].x * iv, a[0].y * iv);
        p.y = pack_bf16(a[1].x * iv, a[1].y * iv);
        p.z = pack_bf16(a[2].x * iv, a[2].y * iv);
        p.w = pack_bf16(a[3].x * iv, a[3].y * iv);
        *((uint4*)(xs + st * XST + lx * 8)) = p;
    }
    __syncthreads();

    // ---- phase 2: MFMA y = x @ W^T; 8 waves, rows 2x16, cols 4x32 ----
    {
        const int wave = t >> 6, lane = t & 63;
        const int row_off = (wave >> 2) * 16;
        const int col_off = (wave & 3) * 32;
        const int lm   = lane & 15;
        const int quad = lane >> 4;
        f32x4 acc[2] = {f32x4{0,0,0,0}, f32x4{0,0,0,0}};
        const ushort* xrow = xs + (row_off + lm) * XST + quad * 8;   // LDS
        const ushort* __restrict__ wrow = wb + (size_t)(col_off + lm) * DIM + quad * 8;
        #pragma unroll
        for (int kk = 0; kk < 4; ++kk) {
            const bf16x8 af = __builtin_bit_cast(bf16x8, *(const u32x4*)(xrow + kk * 32));
            #pragma unroll
            for (int c = 0; c < 2; ++c) {
                const bf16x8 bfr = __builtin_bit_cast(bf16x8,
                    *(const u32x4*)(wrow + (size_t)c * 16 * DIM + kk * 32));
                acc[c] = __builtin_amdgcn_mfma_f32_16x16x32_bf16(af, bfr, acc[c], 0, 0, 0);
            }
        }
        #pragma unroll
        for (int c = 0; c < 2; ++c) {
            #pragma unroll
            for (int r = 0; r < 4; ++r)
                ys[(row_off + quad * 4 + r) * RST + col_off + c * 16 + lm] = acc[c][r];
        }
    }
    __syncthreads();

    // ---- phase 3: LN + ELU; 16 threads per row, 8 dims each ----
    {
        const int r   = t >> 4;              // row 0..31
        const int seg = t & 15;              // 0..15
        const int db  = seg * 8;
        const float* yr = ys + r * RST + db;
        float vs[8];
        {
            const float4 y0 = ((const float4*)yr)[0];
            const float4 y1 = ((const float4*)yr)[1];
            const float4 b0 = ((const float4*)(bias + db))[0];
            const float4 b1 = ((const float4*)(bias + db))[1];
            vs[0] = y0.x + b0.x; vs[1] = y0.y + b0.y; vs[2] = y0.z + b0.z; vs[3] = y0.w + b0.w;
            vs[4] = y1.x + b1.x; vs[5] = y1.y + b1.y; vs[6] = y1.z + b1.z; vs[7] = y1.w + b1.w;
        }
        float s1 = 0.0f, s2 = 0.0f;
        #pragma unroll
        for (int i = 0; i < 8; ++i) { s1 += vs[i]; s2 += vs[i] * vs[i]; }
        #pragma unroll
        for (int m = 1; m < 16; m <<= 1) {
            s1 += __shfl_xor(s1, m);
            s2 += __shfl_xor(s2, m);
        }
        const float mu  = s1 * (1.0f / 128.0f);
        const float var = s2 * (1.0f / 128.0f) - mu * mu;
        const float rs  = rsqrtf(var + LN_EPS);
        float ov[8];
        {
            const float4 g0 = ((const float4*)(gamma + db))[0];
            const float4 g1 = ((const float4*)(gamma + db))[1];
            const float4 t0 = ((const float4*)(beta + db))[0];
            const float4 t1 = ((const float4*)(beta + db))[1];
            float z;
            z = (vs[0] - mu) * rs * g0.x + t0.x; ov[0] = (z > 0.0f) ? z : __expf(z) - 1.0f;
            z = (vs[1] - mu) * rs * g0.y + t0.y; ov[1] = (z > 0.0f) ? z : __expf(z) - 1.0f;
            z = (vs[2] - mu) * rs * g0.z + t0.z; ov[2] = (z > 0.0f) ? z : __expf(z) - 1.0f;
            z = (vs[3] - mu) * rs * g0.w + t0.w; ov[3] = (z > 0.0f) ? z : __expf(z) - 1.0f;
            z = (vs[4] - mu) * rs * g1.x + t1.x; ov[4] = (z > 0.0f) ? z : __expf(z) - 1.0f;
            z = (vs[5] - mu) * rs * g1.y + t1.y; ov[5] = (z > 0.0f) ? z : __expf(z) - 1.0f;
            z = (vs[6] - mu) * rs * g1.z + t1.z; ov[6] = (z > 0.0f) ? z : __expf(z) - 1.0f;
            z = (vs[7] - mu) * rs * g1.w + t1.w; ov[7] = (z > 0.0f) ? z : __expf(z) - 1.0f;
        }
        const int slot = rows + r;
        if (slot < nr) {
            const int orow = OUT_BY_NODE ? uidmap[slot] : slot;
            if (OUT_BF16) {
                uint4 p;
                p.x = pack_bf16(ov[0], ov[1]);
                p.y = pack_bf16(ov[2], ov[3]);
                p.z = pack_bf16(ov[4], ov[5]);
                p.w = pack_bf16(ov[6], ov[7]);
                *((uint4*)((ushort*)fout + (size_t)orow * DIM + db)) = p;
            } else {
                float* op = (float*)fout + (size_t)orow * DIM + db;
                ((float4*)op)[0] = make_float4(ov[0], ov[1], ov[2], ov[3]);
                ((float4*)op)[1] = make_float4(ov[4], ov[5], ov[6], ov[7]);
            }
        }
    }
}

extern "C" void kernel_launch(void* const* d_in, const int* in_sizes, int n_in,
                              void* d_out, int out_size, void* d_ws, size_t ws_size,
                              hipStream_t stream) {
    const float* emb   = (const float*)d_in[0];
    const float* W     = (const float*)d_in[1];
    const float* bias  = (const float*)d_in[2];
    const float* gamma = (const float*)d_in[3];
    const float* beta  = (const float*)d_in[4];
    const int*   src   = (const int*)d_in[5];
    const int*   dst   = (const int*)d_in[6];
    const int*   uid   = (const int*)d_in[7];

    // workspace layout (~46 MB); feature buffers have a zero pad row at index N_NODES
    const size_t FROW = (size_t)(N_NODES + 1) * DIM;
    ushort* E    = (ushort*)d_ws;                     // (N+1)*128 bf16 (embedding + zero row)
    ushort* T1   = E + FROW;                          // (N+1)*128 bf16
    ushort* T2   = T1 + FROW;                         // (N+1)*128 bf16
    ushort* WB   = T2 + FROW;                         // 3*128*128 bf16
    int*    off  = (int*)(WB + 3 * DIM * DIM);        // 50001 (+pad to 50004)
    int*    bhist = off + (N_NODES + 4);              // 256
    int*    bbase = bhist + 256;                      // 260 (NBUCK+1 +pad)
    int*    bcur  = bbase + 260;                      // 256
    int*    mark  = bcur + 256;                       // 50000
    int*    wl    = mark + N_NODES;                   // 50000
    int*    cnt   = wl + N_NODES;                     // 4 (count + pad)
    int*    pak   = cnt + 4;                          // 800000 packed (src<<8)|(dst&255)
    int*    csr   = pak + N_EDGES;                    // 800000 (+16 overread pad)

    prep_kernel<<<(N_NODES * DIM / 4 + 255) / 256, 256, 0, stream>>>(emb, E, W, WB, bhist, T1, T2, mark, cnt);
    bhist_kernel<<<512, 256, 0, stream>>>(dst, bhist);
    bscan_kernel<<<1, 256, 0, stream>>>(bhist, bbase, bcur, off);
    part_kernel<<<(N_EDGES + PCHUNK - 1) / PCHUNK, 256, 0, stream>>>(src, dst, bcur, pak);
    bucket_kernel<<<NBUCK, 256, 0, stream>>>(pak, bbase, off, csr);
    mark_kernel<<<(N_UID + 255) / 256, 256, 0, stream>>>(uid, off, csr, mark);
    compact_kernel<<<(N_NODES + 255) / 256, 256, 0, stream>>>(mark, wl, cnt);

    const int lblk = (N_NODES + 31) / 32;             // 1563 (worst case for layer 2 too)

    // layer 1: all nodes, E -> T1
    layer_kernel<true, false><<<lblk, 512, 0, stream>>>(E, T1, off, csr, nullptr, WB,
                                                        bias, gamma, beta, N_NODES, nullptr);
    // layer 2: only worklist nodes (uid + in-neighbors), T1 -> T2 (write at node id)
    layer_kernel<true, true><<<lblk, 512, 0, stream>>>(T1, T2, off, csr, wl, WB + DIM * DIM,
                                                       bias + DIM, gamma + DIM, beta + DIM,
                                                       0, cnt);
    // layer 3: only uid nodes, T2 -> d_out (fp32, write at slot)
    layer_kernel<false, false><<<N_UID / 32, 512, 0, stream>>>(T2, (float*)d_out, off, csr, uid,
                                                               WB + 2 * DIM * DIM, bias + 2 * DIM,
                                                               gamma + 2 * DIM, beta + 2 * DIM,
                                                               N_UID, nullptr);
}